// Round 6
// baseline (1674.772 us; speedup 1.0000x reference)
//
#include <hip/hip_runtime.h>

typedef unsigned short u16;
typedef unsigned int   u32;
typedef __attribute__((ext_vector_type(8))) short short8; // 8 x bf16 (4 VGPRs)
typedef __attribute__((ext_vector_type(4))) float f32x4;  // mfma accumulator

#define TSEQ   4096
#define DMODEL 512
#define NHEAD  8
#define HDIM   64
#define NLAYER 6
#define MLPD   2048

#define GPTR(p) (const __attribute__((address_space(1))) void*)(p)
#define LPTR(p) (__attribute__((address_space(3))) void*)(p)

__device__ __forceinline__ u16 f2b(float f) {
  u32 u = __float_as_uint(f);
  u32 r = (u + 0x7fffu + ((u >> 16) & 1u)) >> 16; // RNE
  return (u16)r;
}
__device__ __forceinline__ float b2f(u16 h) { return __uint_as_float(((u32)h) << 16); }

__device__ __forceinline__ short8 ld8g(const u16* p, bool ok) {
  if (ok) return *(const short8*)p;
  short8 z = {0, 0, 0, 0, 0, 0, 0, 0};
  return z;
}

// ---------------- merged weight transpose + fp32->bf16 convert ------------
__global__ __launch_bounds__(256) void transpose_convert_all(
    const float* __restrict__ wq, const float* __restrict__ wk,
    const float* __restrict__ wv, const float* __restrict__ wo,
    const float* __restrict__ w1, const float* __restrict__ w2,
    u16* __restrict__ wqkv_bt, u16* __restrict__ wo_bt,
    u16* __restrict__ w1_bt, u16* __restrict__ w2_bt) {
  __shared__ float tile[64][65];
  int bx = blockIdx.x, l = blockIdx.y;
  const float* W; u16* out; int K, N, Ntot, ro, kb, nb2;
  if (bx < 256) {
    int which = bx >> 6, local = bx & 63;
    K = 512; N = 512; kb = local & 7; nb2 = local >> 3;
    if (which == 0)      { W = wq; out = wqkv_bt; Ntot = 1536; ro = 0; }
    else if (which == 1) { W = wk; out = wqkv_bt; Ntot = 1536; ro = 512; }
    else if (which == 2) { W = wv; out = wqkv_bt; Ntot = 1536; ro = 1024; }
    else                 { W = wo; out = wo_bt;   Ntot = 512;  ro = 0; }
  } else if (bx < 512) {
    int local = bx - 256;
    W = w1; out = w1_bt; K = 512; N = 2048; Ntot = 2048; ro = 0;
    kb = local & 7; nb2 = local >> 3;
  } else {
    int local = bx - 512;
    W = w2; out = w2_bt; K = 2048; N = 512; Ntot = 512; ro = 0;
    kb = local >> 3; nb2 = local & 7;
  }
  int k0 = kb * 64, n0 = nb2 * 64;
  const float* Wl = W + (size_t)l * K * N;
  u16* Ol = out + (size_t)l * Ntot * K;
  int tx = threadIdx.x & 15, ty = threadIdx.x >> 4;
#pragma unroll
  for (int p = 0; p < 4; ++p) {
    int k = k0 + p * 16 + ty;
    float4 v = *(const float4*)(Wl + (size_t)k * N + n0 + tx * 4);
    tile[p * 16 + ty][tx * 4 + 0] = v.x;
    tile[p * 16 + ty][tx * 4 + 1] = v.y;
    tile[p * 16 + ty][tx * 4 + 2] = v.z;
    tile[p * 16 + ty][tx * 4 + 3] = v.w;
  }
  __syncthreads();
#pragma unroll
  for (int p = 0; p < 4; ++p) {
    int n = n0 + p * 16 + ty;
    ushort4 s;
    s.x = f2b(tile[tx * 4 + 0][p * 16 + ty]);
    s.y = f2b(tile[tx * 4 + 1][p * 16 + ty]);
    s.z = f2b(tile[tx * 4 + 2][p * 16 + ty]);
    s.w = f2b(tile[tx * 4 + 3][p * 16 + ty]);
    *(ushort4*)(Ol + (size_t)(ro + n) * K + k0 + tx * 4) = s;
  }
}

// ---------------- embedding + sinusoidal PE -------------------------------
__global__ void embed_pe_kernel(const int* __restrict__ idx,
                                const float* __restrict__ embed,
                                float* __restrict__ x) {
  int i = blockIdx.x;
  int t = i & (TSEQ - 1);
  int tok = idx[i];
  int c = threadIdx.x * 4;
  float4 e = *(const float4*)(embed + (size_t)tok * DMODEL + c);
  float vals[4] = {e.x, e.y, e.z, e.w};
  float o[4];
#pragma unroll
  for (int j = 0; j < 4; ++j) {
    int col = c + j;
    int jj = (col < 256) ? col : col - 256;
    float div = __expf((float)jj * -0.035977892078032f);
    float arg = (float)t * div;
    o[j] = vals[j] + ((col < 256) ? __sinf(arg) : __cosf(arg));
  }
  float4 r = {o[0], o[1], o[2], o[3]};
  *(float4*)(x + (size_t)i * DMODEL + c) = r;
}

// ---------------- LayerNorm (wave per row, 2-pass) ------------------------
template <bool OUT_BF16>
__global__ __launch_bounds__(256) void ln_kernel(
    const float* __restrict__ x, const float* __restrict__ gamma,
    const float* __restrict__ beta, void* __restrict__ out) {
  int wave = threadIdx.x >> 6, lane = threadIdx.x & 63;
  int row = (blockIdx.x << 2) + wave;
  const float* xr = x + (size_t)row * DMODEL + lane * 8;
  float4 a = *(const float4*)xr;
  float4 b = *(const float4*)(xr + 4);
  float v[8] = {a.x, a.y, a.z, a.w, b.x, b.y, b.z, b.w};
  float s = 0.f;
#pragma unroll
  for (int j = 0; j < 8; ++j) s += v[j];
#pragma unroll
  for (int off = 1; off < 64; off <<= 1) s += __shfl_xor(s, off, 64);
  float mean = s * (1.0f / 512.0f);
  float q = 0.f;
#pragma unroll
  for (int j = 0; j < 8; ++j) { float d = v[j] - mean; q += d * d; }
#pragma unroll
  for (int off = 1; off < 64; off <<= 1) q += __shfl_xor(q, off, 64);
  float rstd = rsqrtf(q * (1.0f / 512.0f) + 1e-6f);
  float4 g0 = *(const float4*)(gamma + lane * 8);
  float4 g1 = *(const float4*)(gamma + lane * 8 + 4);
  float4 p0 = *(const float4*)(beta + lane * 8);
  float4 p1 = *(const float4*)(beta + lane * 8 + 4);
  float g[8] = {g0.x, g0.y, g0.z, g0.w, g1.x, g1.y, g1.z, g1.w};
  float be[8] = {p0.x, p0.y, p0.z, p0.w, p1.x, p1.y, p1.z, p1.w};
  float r[8];
#pragma unroll
  for (int j = 0; j < 8; ++j) r[j] = (v[j] - mean) * rstd * g[j] + be[j];
  if (OUT_BF16) {
    uint4 pk;
    pk.x = (u32)f2b(r[0]) | ((u32)f2b(r[1]) << 16);
    pk.y = (u32)f2b(r[2]) | ((u32)f2b(r[3]) << 16);
    pk.z = (u32)f2b(r[4]) | ((u32)f2b(r[5]) << 16);
    pk.w = (u32)f2b(r[6]) | ((u32)f2b(r[7]) << 16);
    *(uint4*)((u16*)out + (size_t)row * DMODEL + lane * 8) = pk;
  } else {
    float4 r0 = {r[0], r[1], r[2], r[3]};
    float4 r1 = {r[4], r[5], r[6], r[7]};
    float* op = (float*)out + (size_t)row * DMODEL + lane * 8;
    *(float4*)op = r0;
    *(float4*)(op + 4) = r1;
  }
}

// ---------------- bf16 MFMA GEMM 256x256 tile, 8-phase schedule -----------
// 512 threads = 8 waves (2 M x 4 N), per-wave 128x64 output, BK=64,
// double-buffered LDS (2 x 32KB A + 2 x 32KB B). Blocked 16x32 subtiles with
// XOR-bit5 swizzle; global_load_lds writes linearly with inverse-swizzled
// per-lane global source. Counted vmcnt(4) at tile boundaries (never 0 in
// steady state). FLAGS: 1=bias, 2=relu, 4=fp32 resid, 8=bf16 out, 16=QKV split.
template <int FLAGS>
__global__ __launch_bounds__(512, 2) void gemm256_kernel(
    const u16* __restrict__ A, const u16* __restrict__ Bt,
    const float* __restrict__ bias, const float* __restrict__ resid,
    void* __restrict__ out, void* __restrict__ out2, int M, int N, int K) {
  __shared__ __align__(16) u16 a_lds[2][16384]; // 2 x 32 KB
  __shared__ __align__(16) u16 b_lds[2][16384];
  int m0 = blockIdx.y * 256, n0 = blockIdx.x * 256;
  int tid = threadIdx.x;
  int w = tid >> 6, lane = tid & 63;
  int fr = lane & 15, quad = lane >> 4;
  int wms = (w >> 2) * 8;  // A subtile-row base (8 subtiles = 128 rows)
  int wns = (w & 3) * 4;   // B subtile-row base (4 subtiles = 64 rows)
  int rS = lane >> 2;
  int cS = ((lane & 3) * 8) ^ ((lane & 32) ? 16 : 0);
  const u16* Asrc = A + (size_t)(m0 + w * 16 + rS) * K + cS;
  const u16* Bsrc = Bt + (size_t)(n0 + w * 16 + rS) * K + cS;
  int wBase = w * 1024 + lane * 8; // u16 units
  int rdoff = fr * 32 + ((quad * 8) ^ ((fr & 8) ? 16 : 0));
  int NT = K >> 6;

  f32x4 acc[8][4];
  f32x4 zz = {0.f, 0.f, 0.f, 0.f};
#pragma unroll
  for (int i = 0; i < 8; ++i)
#pragma unroll
    for (int j = 0; j < 4; ++j) acc[i][j] = zz;

  auto stage_half = [&](int hh) {
    if (hh >= 4 * NT) return;
    int th = hh >> 2, part = hh & 3, kk = part >> 1;
    const u16* src = (part & 1) ? Bsrc : Asrc;
    u16* ldsb = (part & 1) ? &b_lds[0][0] : &a_lds[0][0];
    ldsb += (size_t)(th & 1) * 16384;
    src += (size_t)th * 64 + kk * 32;
#pragma unroll
    for (int j = 0; j < 2; ++j) {
      __builtin_amdgcn_global_load_lds(GPTR(src + (size_t)j * 128 * K),
                                       LPTR(ldsb + kk * 512 + j * 8192 + wBase),
                                       16, 0, 0);
    }
  };

#pragma unroll
  for (int hh = 0; hh < 6; ++hh) stage_half(hh);
  asm volatile("s_waitcnt vmcnt(4)\n\ts_barrier" ::: "memory"); // tile0 landed

  for (int t = 0; t < NT; ++t) {
    const u16* ap = a_lds[t & 1];
    const u16* bp = b_lds[t & 1];
    short8 aF[4], bF[4];
#define LDA256(mi_, kk_) (*(const short8*)&ap[((wms + (mi_)) * 2 + (kk_)) * 512 + rdoff])
#define LDB256(ni_, kk_) (*(const short8*)&bp[((wns + (ni_)) * 2 + (kk_)) * 512 + rdoff])
    // ---- phase 0: kk0, mi 0..3 ----
#pragma unroll
    for (int ni = 0; ni < 4; ++ni) bF[ni] = LDB256(ni, 0);
#pragma unroll
    for (int mi = 0; mi < 4; ++mi) aF[mi] = LDA256(mi, 0);
    stage_half(4 * t + 6);
    __builtin_amdgcn_s_barrier();
    __builtin_amdgcn_s_setprio(1);
#pragma unroll
    for (int mi = 0; mi < 4; ++mi)
#pragma unroll
      for (int ni = 0; ni < 4; ++ni)
        acc[mi][ni] = __builtin_amdgcn_mfma_f32_16x16x32_bf16(
            aF[mi], bF[ni], acc[mi][ni], 0, 0, 0);
    __builtin_amdgcn_s_setprio(0);
    __builtin_amdgcn_s_barrier();
    // ---- phase 1: kk0, mi 4..7 ----
#pragma unroll
    for (int mi = 0; mi < 4; ++mi) aF[mi] = LDA256(4 + mi, 0);
    stage_half(4 * t + 7);
    __builtin_amdgcn_s_barrier();
    __builtin_amdgcn_s_setprio(1);
#pragma unroll
    for (int mi = 0; mi < 4; ++mi)
#pragma unroll
      for (int ni = 0; ni < 4; ++ni)
        acc[4 + mi][ni] = __builtin_amdgcn_mfma_f32_16x16x32_bf16(
            aF[mi], bF[ni], acc[4 + mi][ni], 0, 0, 0);
    __builtin_amdgcn_s_setprio(0);
    __builtin_amdgcn_s_barrier();
    // ---- phase 2: kk1, mi 0..3 ----
#pragma unroll
    for (int ni = 0; ni < 4; ++ni) bF[ni] = LDB256(ni, 1);
#pragma unroll
    for (int mi = 0; mi < 4; ++mi) aF[mi] = LDA256(mi, 1);
    stage_half(4 * t + 8);
    __builtin_amdgcn_s_barrier();
    __builtin_amdgcn_s_setprio(1);
#pragma unroll
    for (int mi = 0; mi < 4; ++mi)
#pragma unroll
      for (int ni = 0; ni < 4; ++ni)
        acc[mi][ni] = __builtin_amdgcn_mfma_f32_16x16x32_bf16(
            aF[mi], bF[ni], acc[mi][ni], 0, 0, 0);
    __builtin_amdgcn_s_setprio(0);
    __builtin_amdgcn_s_barrier();
    // ---- phase 3: kk1, mi 4..7 ----
#pragma unroll
    for (int mi = 0; mi < 4; ++mi) aF[mi] = LDA256(4 + mi, 1);
    stage_half(4 * t + 9);
    __builtin_amdgcn_s_barrier();
    __builtin_amdgcn_s_setprio(1);
#pragma unroll
    for (int mi = 0; mi < 4; ++mi)
#pragma unroll
      for (int ni = 0; ni < 4; ++ni)
        acc[4 + mi][ni] = __builtin_amdgcn_mfma_f32_16x16x32_bf16(
            aF[mi], bF[ni], acc[4 + mi][ni], 0, 0, 0);
    __builtin_amdgcn_s_setprio(0);
    if (t + 2 == NT)
      asm volatile("s_waitcnt vmcnt(0)\n\ts_barrier" ::: "memory");
    else if (t + 1 < NT)
      asm volatile("s_waitcnt vmcnt(4)\n\ts_barrier" ::: "memory");
#undef LDA256
#undef LDB256
  }

  int wm = (w >> 2) * 128, wn = (w & 3) * 64;
  if (FLAGS & 16) {
#pragma unroll
    for (int mi = 0; mi < 8; ++mi)
#pragma unroll
      for (int ni = 0; ni < 4; ++ni) {
        int colg = n0 + wn + ni * 16 + fr;
        if (colg < 1024) {
#pragma unroll
          for (int r = 0; r < 4; ++r) {
            int rowg = m0 + wm + mi * 16 + quad * 4 + r;
            ((u16*)out)[(size_t)rowg * 1024 + colg] = f2b(acc[mi][ni][r]);
          }
        } else {
          int hh = (colg - 1024) >> 6, ff = colg & 63;
          int rowg0 = m0 + wm + mi * 16 + quad * 4;
          int bb2 = rowg0 >> 12, tok = rowg0 & 4095;
          ushort4 pk;
          pk.x = f2b(acc[mi][ni][0]);
          pk.y = f2b(acc[mi][ni][1]);
          pk.z = f2b(acc[mi][ni][2]);
          pk.w = f2b(acc[mi][ni][3]);
          *(ushort4*)((u16*)out2 +
                      ((size_t)(bb2 * 8 + hh) * 64 + ff) * 4096 + tok) = pk;
        }
      }
    return;
  }

#pragma unroll
  for (int mi = 0; mi < 8; ++mi)
#pragma unroll
    for (int ni = 0; ni < 4; ++ni) {
      int colg = n0 + wn + ni * 16 + fr;
      float bv = (FLAGS & 1) ? bias[colg] : 0.0f;
#pragma unroll
      for (int r = 0; r < 4; ++r) {
        int rowg = m0 + wm + mi * 16 + quad * 4 + r;
        float val = acc[mi][ni][r] + bv;
        if (FLAGS & 2) val = fmaxf(val, 0.0f);
        if (FLAGS & 4) val += resid[(size_t)rowg * N + colg];
        if (FLAGS & 8)
          ((u16*)out)[(size_t)rowg * N + colg] = f2b(val);
        else
          ((float*)out)[(size_t)rowg * N + colg] = val;
      }
    }
}

// ---------------- bf16 MFMA GEMM 256x128 tile, 8-phase schedule -----------
// Same verified schedule skeleton as gemm256_kernel, B-side halved for
// N=512 GEMMs (grid (N/128, M/256) = 256 blocks = exactly one CU round).
// 512 threads = 8 waves (4 M x 2 N), per-wave 64x64 output, BK=64.
// LDS: A 2x32KB (16 subtiles/buffer), B 2x16KB (8 subtiles/buffer) = 96KB.
// Stage units per K-tile: U0=A-kk0 (2 loads), U1=B-kk0 (1), U2=A-kk1 (2),
// U3=B-kk1 (1). Phase p of tile t stages unit 4t+6+p (U2,U3 of t+1 in
// phases 0,1 -> other buffer; U0,U1 of t+2 in phases 2,3 -> this buffer,
// regions dead since phases 1,0 resp.). Tile boundary: vmcnt(3) (U0,U1 of
// t+2 = 3 loads in flight), vmcnt(0) only before the last tile.
// FLAGS: 1=bias, 2=relu, 4=fp32 resid, 8=bf16 out (else fp32 out)
template <int FLAGS>
__global__ __launch_bounds__(512, 2) void gemm256x128_kernel(
    const u16* __restrict__ A, const u16* __restrict__ Bt,
    const float* __restrict__ bias, const float* __restrict__ resid,
    void* __restrict__ out, int M, int N, int K) {
  __shared__ __align__(16) u16 a_lds[2][16384]; // 2 x 32 KB
  __shared__ __align__(16) u16 b_lds[2][8192];  // 2 x 16 KB
  int m0 = blockIdx.y * 256, n0 = blockIdx.x * 128;
  int tid = threadIdx.x;
  int w = tid >> 6, lane = tid & 63;
  int fr = lane & 15, quad = lane >> 4;
  int wms = (w >> 1) * 4;  // A subtile base (4 subtiles = 64 rows)
  int wns = (w & 1) * 4;   // B subtile base (4 subtiles = 64 cols)
  int rS = lane >> 2;
  int cS = ((lane & 3) * 8) ^ ((lane & 32) ? 16 : 0);
  const u16* Asrc = A + (size_t)(m0 + w * 16 + rS) * K + cS;
  const u16* Bsrc = Bt + (size_t)(n0 + w * 16 + rS) * K + cS;
  int wBase = w * 1024 + lane * 8; // u16 units
  int rdoff = fr * 32 + ((quad * 8) ^ ((fr & 8) ? 16 : 0));
  int NT = K >> 6;

  f32x4 acc[4][4];
  f32x4 zz = {0.f, 0.f, 0.f, 0.f};
#pragma unroll
  for (int i = 0; i < 4; ++i)
#pragma unroll
    for (int j = 0; j < 4; ++j) acc[i][j] = zz;

  // unit g: g>>2 = tile, g&3 = {A-kk0, B-kk0, A-kk1, B-kk1}
  auto stage_unit = [&](int g) {
    if (g >= 4 * NT) return;
    int th = g >> 2, part = g & 3, kk = part >> 1;
    if (part & 1) {
      const u16* src = Bsrc + (size_t)th * 64 + kk * 32;
      u16* ldsb = &b_lds[th & 1][0];
      __builtin_amdgcn_global_load_lds(GPTR(src), LPTR(ldsb + kk * 512 + wBase),
                                       16, 0, 0);
    } else {
      const u16* src = Asrc + (size_t)th * 64 + kk * 32;
      u16* ldsb = &a_lds[th & 1][0];
#pragma unroll
      for (int j = 0; j < 2; ++j) {
        __builtin_amdgcn_global_load_lds(GPTR(src + (size_t)j * 128 * K),
                                         LPTR(ldsb + kk * 512 + j * 8192 + wBase),
                                         16, 0, 0);
      }
    }
  };

  // prologue: tile0 fully (6 loads) + tile1 kk0 units (3 loads)
#pragma unroll
  for (int g = 0; g < 6; ++g) stage_unit(g);
  asm volatile("s_waitcnt vmcnt(3)\n\ts_barrier" ::: "memory"); // tile0 landed

  for (int t = 0; t < NT; ++t) {
    const u16* ap = a_lds[t & 1];
    const u16* bp = b_lds[t & 1];
    short8 bF[4], a0, a1;
#define LDA(mi_, kk_) (*(const short8*)&ap[((wms + (mi_)) * 2 + (kk_)) * 512 + rdoff])
#define LDB(ni_, kk_) (*(const short8*)&bp[((wns + (ni_)) * 2 + (kk_)) * 512 + rdoff])
    // ---- phase 0: kk0, mi 0..1 ----
#pragma unroll
    for (int ni = 0; ni < 4; ++ni) bF[ni] = LDB(ni, 0);
    a0 = LDA(0, 0); a1 = LDA(1, 0);
    stage_unit(4 * t + 6); // A-kk1 of tile t+1 (other buffer)
    __builtin_amdgcn_s_barrier();
    __builtin_amdgcn_s_setprio(1);
#pragma unroll
    for (int ni = 0; ni < 4; ++ni)
      acc[0][ni] = __builtin_amdgcn_mfma_f32_16x16x32_bf16(a0, bF[ni], acc[0][ni], 0, 0, 0);
#pragma unroll
    for (int ni = 0; ni < 4; ++ni)
      acc[1][ni] = __builtin_amdgcn_mfma_f32_16x16x32_bf16(a1, bF[ni], acc[1][ni], 0, 0, 0);
    __builtin_amdgcn_s_setprio(0);
    __builtin_amdgcn_s_barrier();
    // ---- phase 1: kk0, mi 2..3 ----
    a0 = LDA(2, 0); a1 = LDA(3, 0);
    stage_unit(4 * t + 7); // B-kk1 of tile t+1 (other buffer)
    __builtin_amdgcn_s_barrier();
    __builtin_amdgcn_s_setprio(1);
#pragma unroll
    for (int ni = 0; ni < 4; ++ni)
      acc[2][ni] = __builtin_amdgcn_mfma_f32_16x16x32_bf16(a0, bF[ni], acc[2][ni], 0, 0, 0);
#pragma unroll
    for (int ni = 0; ni < 4; ++ni)
      acc[3][ni] = __builtin_amdgcn_mfma_f32_16x16x32_bf16(a1, bF[ni], acc[3][ni], 0, 0, 0);
    __builtin_amdgcn_s_setprio(0);
    __builtin_amdgcn_s_barrier();
    // ---- phase 2: kk1, mi 0..1 ----
#pragma unroll
    for (int ni = 0; ni < 4; ++ni) bF[ni] = LDB(ni, 1);
    a0 = LDA(0, 1); a1 = LDA(1, 1);
    stage_unit(4 * t + 8); // A-kk0 of tile t+2 (this buffer; dead since phase 1)
    __builtin_amdgcn_s_barrier();
    __builtin_amdgcn_s_setprio(1);
#pragma unroll
    for (int ni = 0; ni < 4; ++ni)
      acc[0][ni] = __builtin_amdgcn_mfma_f32_16x16x32_bf16(a0, bF[ni], acc[0][ni], 0, 0, 0);
#pragma unroll
    for (int ni = 0; ni < 4; ++ni)
      acc[1][ni] = __builtin_amdgcn_mfma_f32_16x16x32_bf16(a1, bF[ni], acc[1][ni], 0, 0, 0);
    __builtin_amdgcn_s_setprio(0);
    __builtin_amdgcn_s_barrier();
    // ---- phase 3: kk1, mi 2..3 ----
    a0 = LDA(2, 1); a1 = LDA(3, 1);
    stage_unit(4 * t + 9); // B-kk0 of tile t+2 (this buffer; dead since phase 0)
    __builtin_amdgcn_s_barrier();
    __builtin_amdgcn_s_setprio(1);
#pragma unroll
    for (int ni = 0; ni < 4; ++ni)
      acc[2][ni] = __builtin_amdgcn_mfma_f32_16x16x32_bf16(a0, bF[ni], acc[2][ni], 0, 0, 0);
#pragma unroll
    for (int ni = 0; ni < 4; ++ni)
      acc[3][ni] = __builtin_amdgcn_mfma_f32_16x16x32_bf16(a1, bF[ni], acc[3][ni], 0, 0, 0);
    __builtin_amdgcn_s_setprio(0);
    if (t + 2 == NT)
      asm volatile("s_waitcnt vmcnt(0)\n\ts_barrier" ::: "memory");
    else if (t + 1 < NT)
      asm volatile("s_waitcnt vmcnt(3)\n\ts_barrier" ::: "memory");
#undef LDA
#undef LDB
  }

  int wm = (w >> 1) * 64, wn = (w & 1) * 64;
#pragma unroll
  for (int mi = 0; mi < 4; ++mi)
#pragma unroll
    for (int ni = 0; ni < 4; ++ni) {
      int colg = n0 + wn + ni * 16 + fr;
      float bv = (FLAGS & 1) ? bias[colg] : 0.0f;
#pragma unroll
      for (int r = 0; r < 4; ++r) {
        int rowg = m0 + wm + mi * 16 + quad * 4 + r;
        float val = acc[mi][ni][r] + bv;
        if (FLAGS & 2) val = fmaxf(val, 0.0f);
        if (FLAGS & 4) val += resid[(size_t)rowg * N + colg];
        if (FLAGS & 8)
          ((u16*)out)[(size_t)rowg * N + colg] = f2b(val);
        else
          ((float*)out)[(size_t)rowg * N + colg] = val;
      }
    }
}

// ---------------- MFMA local block attention ------------------------------
__global__ __launch_bounds__(128) void attn_mfma_kernel(
    const u16* __restrict__ qk, const u16* __restrict__ vt,
    const int* __restrict__ tokens, u16* __restrict__ o, int sh) {
  __shared__ __align__(16) u16 ps[2][64][72];
  __shared__ float kmask[64];
  int n = blockIdx.x, hg = blockIdx.y, b = blockIdx.z;
  int tid = threadIdx.x;
  int w = tid >> 6, lane = tid & 63;
  int head = hg * 2 + w;
  int fr = lane & 15, quad = lane >> 4;

  if (tid < 64) {
    int pp = n * 64 + tid - sh;
    kmask[tid] =
        (pp >= 0 && pp < TSEQ && tokens[(size_t)b * TSEQ + pp] > 0) ? 1.f : 0.f;
  }
  __syncthreads();

  const u16* qkb = qk + (size_t)b * TSEQ * 1024;

  f32x4 st[4][4];
  f32x4 zz = {0.f, 0.f, 0.f, 0.f};
#pragma unroll
  for (int i = 0; i < 4; ++i)
#pragma unroll
    for (int j = 0; j < 4; ++j) st[i][j] = zz;
#pragma unroll
  for (int kk = 0; kk < 2; ++kk) {
    short8 ka[4], qb[4];
#pragma unroll
    for (int mi = 0; mi < 4; ++mi) {
      int p = n * 64 + mi * 16 + fr - sh;
      ka[mi] = ld8g(qkb + (ptrdiff_t)p * 1024 + 512 + head * 64 + kk * 32 + quad * 8,
                    p >= 0 && p < TSEQ);
    }
#pragma unroll
    for (int ni = 0; ni < 4; ++ni) {
      int p = n * 64 + ni * 16 + fr - sh;
      qb[ni] = ld8g(qkb + (ptrdiff_t)p * 1024 + head * 64 + kk * 32 + quad * 8,
                    p >= 0 && p < TSEQ);
    }
#pragma unroll
    for (int mi = 0; mi < 4; ++mi)
#pragma unroll
      for (int ni = 0; ni < 4; ++ni)
        st[mi][ni] = __builtin_amdgcn_mfma_f32_16x16x32_bf16(
            ka[mi], qb[ni], st[mi][ni], 0, 0, 0);
  }

  float kmv[4][4];
#pragma unroll
  for (int mi = 0; mi < 4; ++mi)
#pragma unroll
    for (int r = 0; r < 4; ++r) kmv[mi][r] = kmask[mi * 16 + quad * 4 + r];
#pragma unroll
  for (int ni = 0; ni < 4; ++ni) {
    float mx = -3.0e38f;
#pragma unroll
    for (int mi = 0; mi < 4; ++mi)
#pragma unroll
      for (int r = 0; r < 4; ++r) {
        float s = (kmv[mi][r] > 0.f) ? st[mi][ni][r] * 0.125f : -1.0e9f;
        st[mi][ni][r] = s;
        mx = fmaxf(mx, s);
      }
    mx = fmaxf(mx, __shfl_xor(mx, 16, 64));
    mx = fmaxf(mx, __shfl_xor(mx, 32, 64));
    float sm = 0.f;
#pragma unroll
    for (int mi = 0; mi < 4; ++mi)
#pragma unroll
      for (int r = 0; r < 4; ++r) {
        float e = __expf(st[mi][ni][r] - mx);
        st[mi][ni][r] = e;
        sm += e;
      }
    sm += __shfl_xor(sm, 16, 64);
    sm += __shfl_xor(sm, 32, 64);
    float inv = 1.0f / sm;
#pragma unroll
    for (int mi = 0; mi < 4; ++mi)
#pragma unroll
      for (int r = 0; r < 4; ++r) st[mi][ni][r] *= inv;
  }

#pragma unroll
  for (int mi = 0; mi < 4; ++mi)
#pragma unroll
    for (int ni = 0; ni < 4; ++ni) {
      uint2 pk;
      pk.x = (u32)f2b(st[mi][ni][0]) | ((u32)f2b(st[mi][ni][1]) << 16);
      pk.y = (u32)f2b(st[mi][ni][2]) | ((u32)f2b(st[mi][ni][3]) << 16);
      *(uint2*)&ps[w][ni * 16 + fr][mi * 16 + quad * 4] = pk;
    }
  __syncthreads();

  f32x4 oc[4][4];
#pragma unroll
  for (int i = 0; i < 4; ++i)
#pragma unroll
    for (int j = 0; j < 4; ++j) oc[i][j] = zz;
  const u16* vtb = vt + (size_t)(b * 8 + head) * 64 * 4096;
#pragma unroll
  for (int kk = 0; kk < 2; ++kk) {
    short8 pa[4], vb[4];
#pragma unroll
    for (int mi = 0; mi < 4; ++mi)
      pa[mi] = *(const short8*)&ps[w][mi * 16 + fr][kk * 32 + quad * 8];
    int key0 = n * 64 - sh + kk * 32 + quad * 8;
    bool kok = (key0 >= 0) && (key0 < TSEQ);
#pragma unroll
    for (int ni = 0; ni < 4; ++ni)
      vb[ni] = ld8g(vtb + (size_t)(ni * 16 + fr) * 4096 + key0, kok);
#pragma unroll
    for (int mi = 0; mi < 4; ++mi)
#pragma unroll
      for (int ni = 0; ni < 4; ++ni)
        oc[mi][ni] = __builtin_amdgcn_mfma_f32_16x16x32_bf16(
            pa[mi], vb[ni], oc[mi][ni], 0, 0, 0);
  }

#pragma unroll
  for (int mi = 0; mi < 4; ++mi)
#pragma unroll
    for (int ni = 0; ni < 4; ++ni)
#pragma unroll
      for (int r = 0; r < 4; ++r) {
        int q = mi * 16 + quad * 4 + r;
        int p = n * 64 + q - sh;
        if (p >= 0 && p < TSEQ)
          o[((size_t)(b * TSEQ + p)) * DMODEL + head * 64 + ni * 16 + fr] =
              f2b(oc[mi][ni][r]);
      }
}

// ---------------------------------------------------------------------------
extern "C" void kernel_launch(void* const* d_in, const int* in_sizes, int n_in,
                              void* d_out, int out_size, void* d_ws, size_t ws_size,
                              hipStream_t stream) {
  (void)in_sizes; (void)n_in; (void)out_size; (void)ws_size;
  const int*   tokens = (const int*)d_in[0];
  const float* embed  = (const float*)d_in[1];
  const float* wq = (const float*)d_in[2];
  const float* wk = (const float*)d_in[3];
  const float* wv = (const float*)d_in[4];
  const float* wo = (const float*)d_in[5];
  const float* ln1_s = (const float*)d_in[6];
  const float* ln1_b = (const float*)d_in[7];
  const float* ln2_s = (const float*)d_in[8];
  const float* ln2_b = (const float*)d_in[9];
  const float* w1 = (const float*)d_in[10];
  const float* b1 = (const float*)d_in[11];
  const float* w2 = (const float*)d_in[12];
  const float* b2 = (const float*)d_in[13];
  const float* lnf_s = (const float*)d_in[14];
  const float* lnf_b = (const float*)d_in[15];

  char* ws = (char*)d_ws;
  const size_t MB = 1024ull * 1024ull;
  float* x     = (float*)(ws + 0);        // 32 MB fp32 residual
  u16* h       = (u16*)(ws + 32 * MB);    // 16 MB bf16 LN out
  u16* qk      = (u16*)(ws + 48 * MB);    // 33.5 MB bf16 [B*T][1024]
  u16* vt      = (u16*)(ws + 82 * MB);    // 16.8 MB bf16 V^T
  u16* obuf    = (u16*)(ws + 99 * MB);    // 16.8 MB bf16
  u16* hidden  = (u16*)(ws + 48 * MB);    // 64 MB (aliases qk/vt/obuf, disjoint in time)
  u16* wqkv_bt = (u16*)(ws + 116 * MB);   // 9 MB
  u16* wo_bt   = (u16*)(ws + 126 * MB);   // 3.1 MB
  u16* w1_bt   = (u16*)(ws + 130 * MB);   // 12.6 MB
  u16* w2_bt   = (u16*)(ws + 143 * MB);   // 12.6 MB (total ~156 MB)

  transpose_convert_all<<<dim3(768, 6), 256, 0, stream>>>(
      wq, wk, wv, wo, w1, w2, wqkv_bt, wo_bt, w1_bt, w2_bt);

  embed_pe_kernel<<<16384, 128, 0, stream>>>(tokens, embed, x);

  for (int l = 0; l < NLAYER; ++l) {
    int sh = (l & 1) ? 32 : 0;
    int nb = (l & 1) ? 65 : 64;
    ln_kernel<true><<<4096, 256, 0, stream>>>(x, ln1_s + l * 512, ln1_b + l * 512, h);
    gemm256_kernel<16><<<dim3(6, 64), 512, 0, stream>>>(
        h, wqkv_bt + (size_t)l * 1536 * 512, nullptr, nullptr, qk, vt,
        16384, 1536, 512);
    attn_mfma_kernel<<<dim3(nb, 4, 4), 128, 0, stream>>>(qk, vt, tokens, obuf, sh);
    gemm256x128_kernel<4><<<dim3(4, 64), 512, 0, stream>>>(
        obuf, wo_bt + (size_t)l * 512 * 512, nullptr, x, x,
        16384, 512, 512);
    ln_kernel<true><<<4096, 256, 0, stream>>>(x, ln2_s + l * 512, ln2_b + l * 512, h);
    gemm256_kernel<1 | 2 | 8><<<dim3(8, 64), 512, 0, stream>>>(
        h, w1_bt + (size_t)l * 2048 * 512, b1 + l * 2048, nullptr, hidden, nullptr,
        16384, 2048, 512);
    gemm256x128_kernel<1 | 4><<<dim3(4, 64), 512, 0, stream>>>(
        hidden, w2_bt + (size_t)l * 512 * 2048, b2 + l * 512, x, x,
        16384, 512, 2048);
  }
  ln_kernel<false><<<4096, 256, 0, stream>>>(x, lnf_s, lnf_b, d_out);
}

// Round 8
// 1494.498 us; speedup vs baseline: 1.1206x; 1.1206x over previous
//
#include <hip/hip_runtime.h>

typedef unsigned short u16;
typedef unsigned int   u32;
typedef __attribute__((ext_vector_type(8))) short short8; // 8 x bf16 (4 VGPRs)
typedef __attribute__((ext_vector_type(4))) float f32x4;  // mfma accumulator

#define TSEQ   4096
#define DMODEL 512
#define NHEAD  8
#define HDIM   64
#define NLAYER 6
#define MLPD   2048

#define GPTR(p) (const __attribute__((address_space(1))) void*)(p)
#define LPTR(p) (__attribute__((address_space(3))) void*)(p)

__device__ __forceinline__ u16 f2b(float f) {
  u32 u = __float_as_uint(f);
  u32 r = (u + 0x7fffu + ((u >> 16) & 1u)) >> 16; // RNE
  return (u16)r;
}
__device__ __forceinline__ float b2f(u16 h) { return __uint_as_float(((u32)h) << 16); }

__device__ __forceinline__ short8 ld8g(const u16* p, bool ok) {
  if (ok) return *(const short8*)p;
  short8 z = {0, 0, 0, 0, 0, 0, 0, 0};
  return z;
}

// XCD-chunked bijective blockIdx swizzle (T1). Requires nwg % 8 == 0 and
// cpx % gridDim.x == 0 (true for all GEMM launches here): tiles sharing a
// row-panel (same by => same A panel) land on one XCD -> A reuse hits the
// XCD-local L2 instead of bouncing through L3.
__device__ __forceinline__ void xcd_swizzle(int& bx, int& by) {
  int gx = gridDim.x;
  int lin = by * gx + bx;
  int nwg = gx * gridDim.y;
  int cpx = nwg >> 3;
  int t = (lin & 7) * cpx + (lin >> 3);
  bx = t % gx;
  by = t / gx;
}

// ---------------- merged weight transpose + fp32->bf16 convert ------------
__global__ __launch_bounds__(256) void transpose_convert_all(
    const float* __restrict__ wq, const float* __restrict__ wk,
    const float* __restrict__ wv, const float* __restrict__ wo,
    const float* __restrict__ w1, const float* __restrict__ w2,
    u16* __restrict__ wqkv_bt, u16* __restrict__ wo_bt,
    u16* __restrict__ w1_bt, u16* __restrict__ w2_bt) {
  __shared__ float tile[64][65];
  int bx = blockIdx.x, l = blockIdx.y;
  const float* W; u16* out; int K, N, Ntot, ro, kb, nb2;
  if (bx < 256) {
    int which = bx >> 6, local = bx & 63;
    K = 512; N = 512; kb = local & 7; nb2 = local >> 3;
    if (which == 0)      { W = wq; out = wqkv_bt; Ntot = 1536; ro = 0; }
    else if (which == 1) { W = wk; out = wqkv_bt; Ntot = 1536; ro = 512; }
    else if (which == 2) { W = wv; out = wqkv_bt; Ntot = 1536; ro = 1024; }
    else                 { W = wo; out = wo_bt;   Ntot = 512;  ro = 0; }
  } else if (bx < 512) {
    int local = bx - 256;
    W = w1; out = w1_bt; K = 512; N = 2048; Ntot = 2048; ro = 0;
    kb = local & 7; nb2 = local >> 3;
  } else {
    int local = bx - 512;
    W = w2; out = w2_bt; K = 2048; N = 512; Ntot = 512; ro = 0;
    kb = local >> 3; nb2 = local & 7;
  }
  int k0 = kb * 64, n0 = nb2 * 64;
  const float* Wl = W + (size_t)l * K * N;
  u16* Ol = out + (size_t)l * Ntot * K;
  int tx = threadIdx.x & 15, ty = threadIdx.x >> 4;
#pragma unroll
  for (int p = 0; p < 4; ++p) {
    int k = k0 + p * 16 + ty;
    float4 v = *(const float4*)(Wl + (size_t)k * N + n0 + tx * 4);
    tile[p * 16 + ty][tx * 4 + 0] = v.x;
    tile[p * 16 + ty][tx * 4 + 1] = v.y;
    tile[p * 16 + ty][tx * 4 + 2] = v.z;
    tile[p * 16 + ty][tx * 4 + 3] = v.w;
  }
  __syncthreads();
#pragma unroll
  for (int p = 0; p < 4; ++p) {
    int n = n0 + p * 16 + ty;
    ushort4 s;
    s.x = f2b(tile[tx * 4 + 0][p * 16 + ty]);
    s.y = f2b(tile[tx * 4 + 1][p * 16 + ty]);
    s.z = f2b(tile[tx * 4 + 2][p * 16 + ty]);
    s.w = f2b(tile[tx * 4 + 3][p * 16 + ty]);
    *(ushort4*)(Ol + (size_t)(ro + n) * K + k0 + tx * 4) = s;
  }
}

// ---------------- embedding + sinusoidal PE -------------------------------
__global__ void embed_pe_kernel(const int* __restrict__ idx,
                                const float* __restrict__ embed,
                                float* __restrict__ x) {
  int i = blockIdx.x;
  int t = i & (TSEQ - 1);
  int tok = idx[i];
  int c = threadIdx.x * 4;
  float4 e = *(const float4*)(embed + (size_t)tok * DMODEL + c);
  float vals[4] = {e.x, e.y, e.z, e.w};
  float o[4];
#pragma unroll
  for (int j = 0; j < 4; ++j) {
    int col = c + j;
    int jj = (col < 256) ? col : col - 256;
    float div = __expf((float)jj * -0.035977892078032f);
    float arg = (float)t * div;
    o[j] = vals[j] + ((col < 256) ? __sinf(arg) : __cosf(arg));
  }
  float4 r = {o[0], o[1], o[2], o[3]};
  *(float4*)(x + (size_t)i * DMODEL + c) = r;
}

// ---------------- LayerNorm (wave per row, 2-pass) ------------------------
template <bool OUT_BF16>
__global__ __launch_bounds__(256) void ln_kernel(
    const float* __restrict__ x, const float* __restrict__ gamma,
    const float* __restrict__ beta, void* __restrict__ out) {
  int wave = threadIdx.x >> 6, lane = threadIdx.x & 63;
  int row = (blockIdx.x << 2) + wave;
  const float* xr = x + (size_t)row * DMODEL + lane * 8;
  float4 a = *(const float4*)xr;
  float4 b = *(const float4*)(xr + 4);
  float v[8] = {a.x, a.y, a.z, a.w, b.x, b.y, b.z, b.w};
  float s = 0.f;
#pragma unroll
  for (int j = 0; j < 8; ++j) s += v[j];
#pragma unroll
  for (int off = 1; off < 64; off <<= 1) s += __shfl_xor(s, off, 64);
  float mean = s * (1.0f / 512.0f);
  float q = 0.f;
#pragma unroll
  for (int j = 0; j < 8; ++j) { float d = v[j] - mean; q += d * d; }
#pragma unroll
  for (int off = 1; off < 64; off <<= 1) q += __shfl_xor(q, off, 64);
  float rstd = rsqrtf(q * (1.0f / 512.0f) + 1e-6f);
  float4 g0 = *(const float4*)(gamma + lane * 8);
  float4 g1 = *(const float4*)(gamma + lane * 8 + 4);
  float4 p0 = *(const float4*)(beta + lane * 8);
  float4 p1 = *(const float4*)(beta + lane * 8 + 4);
  float g[8] = {g0.x, g0.y, g0.z, g0.w, g1.x, g1.y, g1.z, g1.w};
  float be[8] = {p0.x, p0.y, p0.z, p0.w, p1.x, p1.y, p1.z, p1.w};
  float r[8];
#pragma unroll
  for (int j = 0; j < 8; ++j) r[j] = (v[j] - mean) * rstd * g[j] + be[j];
  if (OUT_BF16) {
    uint4 pk;
    pk.x = (u32)f2b(r[0]) | ((u32)f2b(r[1]) << 16);
    pk.y = (u32)f2b(r[2]) | ((u32)f2b(r[3]) << 16);
    pk.z = (u32)f2b(r[4]) | ((u32)f2b(r[5]) << 16);
    pk.w = (u32)f2b(r[6]) | ((u32)f2b(r[7]) << 16);
    *(uint4*)((u16*)out + (size_t)row * DMODEL + lane * 8) = pk;
  } else {
    float4 r0 = {r[0], r[1], r[2], r[3]};
    float4 r1 = {r[4], r[5], r[6], r[7]};
    float* op = (float*)out + (size_t)row * DMODEL + lane * 8;
    *(float4*)op = r0;
    *(float4*)(op + 4) = r1;
  }
}

// ---------------- bf16 MFMA GEMM (128x128 tile, for N=512 GEMMs) ----------
// 3 blocks/CU (48KB LDS) — inter-block overlap hides the staging drain;
// measured faster than the 1-block/CU 256x128 8-phase variant (R6).
// FLAGS: 1=bias, 2=relu, 4=fp32 residual add, 8=bf16 out (else fp32 out)
// 16=QKV split epilogue (qk + transposed V)
template <int FLAGS>
__global__ __launch_bounds__(256) void gemm_kernel(
    const u16* __restrict__ A, const u16* __restrict__ Bt,
    const float* __restrict__ bias, const float* __restrict__ resid,
    void* __restrict__ out, void* __restrict__ out2, int M, int N, int K) {
  __shared__ __align__(16) u16 a_lds[3][128][32]; // 3 x 8 KB
  __shared__ __align__(16) u16 b_lds[3][128][32];
  int bxs = blockIdx.x, bys = blockIdx.y;
  xcd_swizzle(bxs, bys);
  int m0 = bys * 128, n0 = bxs * 128;
  int t = threadIdx.x;
  int lr = t >> 2, lc = (t & 3) * 8;
  int wave = t >> 6, lane = t & 63;
  int wm = (wave >> 1) * 64, wn = (wave & 1) * 64;
  int fr = lane & 15, quad = lane >> 4;

  f32x4 acc[4][4];
  f32x4 zz = {0.f, 0.f, 0.f, 0.f};
#pragma unroll
  for (int i = 0; i < 4; ++i)
#pragma unroll
    for (int j = 0; j < 4; ++j) acc[i][j] = zz;

  const u16* Ag0 = A + (size_t)(m0 + lr) * K + lc;
  const u16* Ag1 = A + (size_t)(m0 + lr + 64) * K + lc;
  const u16* Bg0 = Bt + (size_t)(n0 + lr) * K + lc;
  const u16* Bg1 = Bt + (size_t)(n0 + lr + 64) * K + lc;

  __builtin_amdgcn_global_load_lds(GPTR(Ag0), LPTR(&a_lds[0][lr][lc]), 16, 0, 0);
  __builtin_amdgcn_global_load_lds(GPTR(Ag1), LPTR(&a_lds[0][lr + 64][lc]), 16, 0, 0);
  __builtin_amdgcn_global_load_lds(GPTR(Bg0), LPTR(&b_lds[0][lr][lc]), 16, 0, 0);
  __builtin_amdgcn_global_load_lds(GPTR(Bg1), LPTR(&b_lds[0][lr + 64][lc]), 16, 0, 0);

  int T = K >> 5;
  int buf = 0;
  for (int tt = 0; tt < T; ++tt) {
    int nb = buf + 1 == 3 ? 0 : buf + 1;
    if (tt + 1 < T) {
      int off = (tt + 1) << 5;
      __builtin_amdgcn_global_load_lds(GPTR(Ag0 + off), LPTR(&a_lds[nb][lr][lc]), 16, 0, 0);
      __builtin_amdgcn_global_load_lds(GPTR(Ag1 + off), LPTR(&a_lds[nb][lr + 64][lc]), 16, 0, 0);
      __builtin_amdgcn_global_load_lds(GPTR(Bg0 + off), LPTR(&b_lds[nb][lr][lc]), 16, 0, 0);
      __builtin_amdgcn_global_load_lds(GPTR(Bg1 + off), LPTR(&b_lds[nb][lr + 64][lc]), 16, 0, 0);
      asm volatile("s_waitcnt vmcnt(4)\n\ts_barrier" ::: "memory");
    } else {
      asm volatile("s_waitcnt vmcnt(0)\n\ts_barrier" ::: "memory");
    }
    short8 af[4], bf[4];
#pragma unroll
    for (int mi = 0; mi < 4; ++mi)
      af[mi] = *(const short8*)&a_lds[buf][wm + mi * 16 + fr][quad * 8];
#pragma unroll
    for (int ni = 0; ni < 4; ++ni)
      bf[ni] = *(const short8*)&b_lds[buf][wn + ni * 16 + fr][quad * 8];
#pragma unroll
    for (int mi = 0; mi < 4; ++mi)
#pragma unroll
      for (int ni = 0; ni < 4; ++ni)
        acc[mi][ni] = __builtin_amdgcn_mfma_f32_16x16x32_bf16(
            af[mi], bf[ni], acc[mi][ni], 0, 0, 0);
    buf = nb;
  }

  if (FLAGS & 16) {
#pragma unroll
    for (int mi = 0; mi < 4; ++mi)
#pragma unroll
      for (int ni = 0; ni < 4; ++ni) {
        int colg = n0 + wn + ni * 16 + fr;
        if (colg < 1024) {
#pragma unroll
          for (int r = 0; r < 4; ++r) {
            int rowg = m0 + wm + mi * 16 + quad * 4 + r;
            ((u16*)out)[(size_t)rowg * 1024 + colg] = f2b(acc[mi][ni][r]);
          }
        } else {
          int hh = (colg - 1024) >> 6, ff = colg & 63;
          int rowg0 = m0 + wm + mi * 16 + quad * 4;
          int bb = rowg0 >> 12, tok = rowg0 & 4095;
          ushort4 pk;
          pk.x = f2b(acc[mi][ni][0]);
          pk.y = f2b(acc[mi][ni][1]);
          pk.z = f2b(acc[mi][ni][2]);
          pk.w = f2b(acc[mi][ni][3]);
          *(ushort4*)((u16*)out2 +
                      ((size_t)(bb * 8 + hh) * 64 + ff) * 4096 + tok) = pk;
        }
      }
    return;
  }

#pragma unroll
  for (int mi = 0; mi < 4; ++mi)
#pragma unroll
    for (int ni = 0; ni < 4; ++ni) {
      int colg = n0 + wn + ni * 16 + fr;
      float bv = (FLAGS & 1) ? bias[colg] : 0.0f;
#pragma unroll
      for (int r = 0; r < 4; ++r) {
        int rowg = m0 + wm + mi * 16 + quad * 4 + r;
        float val = acc[mi][ni][r] + bv;
        if (FLAGS & 2) val = fmaxf(val, 0.0f);
        if (FLAGS & 4) val += resid[(size_t)rowg * N + colg];
        if (FLAGS & 8)
          ((u16*)out)[(size_t)rowg * N + colg] = f2b(val);
        else
          ((float*)out)[(size_t)rowg * N + colg] = val;
      }
    }
}

// ---------------- bf16 MFMA GEMM 256x256 tile, 8-phase schedule -----------
// 512 threads = 8 waves (2 M x 4 N), per-wave 128x64 output, BK=64,
// double-buffered LDS (2 x 32KB A + 2 x 32KB B). Blocked 16x32 subtiles with
// XOR-bit5 swizzle; global_load_lds writes linearly with inverse-swizzled
// per-lane global source. Counted vmcnt(4) at tile boundaries (never 0 in
// steady state). FLAGS: 1=bias, 2=relu, 4=fp32 resid, 8=bf16 out, 16=QKV split.
template <int FLAGS>
__global__ __launch_bounds__(512, 2) void gemm256_kernel(
    const u16* __restrict__ A, const u16* __restrict__ Bt,
    const float* __restrict__ bias, const float* __restrict__ resid,
    void* __restrict__ out, void* __restrict__ out2, int M, int N, int K) {
  __shared__ __align__(16) u16 a_lds[2][16384]; // 2 x 32 KB
  __shared__ __align__(16) u16 b_lds[2][16384];
  int bxs = blockIdx.x, bys = blockIdx.y;
  xcd_swizzle(bxs, bys);
  int m0 = bys * 256, n0 = bxs * 256;
  int tid = threadIdx.x;
  int w = tid >> 6, lane = tid & 63;
  int fr = lane & 15, quad = lane >> 4;
  int wms = (w >> 2) * 8;  // A subtile-row base (8 subtiles = 128 rows)
  int wns = (w & 3) * 4;   // B subtile-row base (4 subtiles = 64 rows)
  int rS = lane >> 2;
  int cS = ((lane & 3) * 8) ^ ((lane & 32) ? 16 : 0);
  const u16* Asrc = A + (size_t)(m0 + w * 16 + rS) * K + cS;
  const u16* Bsrc = Bt + (size_t)(n0 + w * 16 + rS) * K + cS;
  int wBase = w * 1024 + lane * 8; // u16 units
  int rdoff = fr * 32 + ((quad * 8) ^ ((fr & 8) ? 16 : 0));
  int NT = K >> 6;

  f32x4 acc[8][4];
  f32x4 zz = {0.f, 0.f, 0.f, 0.f};
#pragma unroll
  for (int i = 0; i < 8; ++i)
#pragma unroll
    for (int j = 0; j < 4; ++j) acc[i][j] = zz;

  auto stage_half = [&](int hh) {
    if (hh >= 4 * NT) return;
    int th = hh >> 2, part = hh & 3, kk = part >> 1;
    const u16* src = (part & 1) ? Bsrc : Asrc;
    u16* ldsb = (part & 1) ? &b_lds[0][0] : &a_lds[0][0];
    ldsb += (size_t)(th & 1) * 16384;
    src += (size_t)th * 64 + kk * 32;
#pragma unroll
    for (int j = 0; j < 2; ++j) {
      __builtin_amdgcn_global_load_lds(GPTR(src + (size_t)j * 128 * K),
                                       LPTR(ldsb + kk * 512 + j * 8192 + wBase),
                                       16, 0, 0);
    }
  };

#pragma unroll
  for (int hh = 0; hh < 6; ++hh) stage_half(hh);
  asm volatile("s_waitcnt vmcnt(4)\n\ts_barrier" ::: "memory"); // tile0 landed

  for (int t = 0; t < NT; ++t) {
    const u16* ap = a_lds[t & 1];
    const u16* bp = b_lds[t & 1];
    short8 aF[4], bF[4];
#define LDA256(mi_, kk_) (*(const short8*)&ap[((wms + (mi_)) * 2 + (kk_)) * 512 + rdoff])
#define LDB256(ni_, kk_) (*(const short8*)&bp[((wns + (ni_)) * 2 + (kk_)) * 512 + rdoff])
    // ---- phase 0: kk0, mi 0..3 ----
#pragma unroll
    for (int ni = 0; ni < 4; ++ni) bF[ni] = LDB256(ni, 0);
#pragma unroll
    for (int mi = 0; mi < 4; ++mi) aF[mi] = LDA256(mi, 0);
    stage_half(4 * t + 6);
    __builtin_amdgcn_s_barrier();
    __builtin_amdgcn_s_setprio(1);
#pragma unroll
    for (int mi = 0; mi < 4; ++mi)
#pragma unroll
      for (int ni = 0; ni < 4; ++ni)
        acc[mi][ni] = __builtin_amdgcn_mfma_f32_16x16x32_bf16(
            aF[mi], bF[ni], acc[mi][ni], 0, 0, 0);
    __builtin_amdgcn_s_setprio(0);
    __builtin_amdgcn_s_barrier();
    // ---- phase 1: kk0, mi 4..7 ----
#pragma unroll
    for (int mi = 0; mi < 4; ++mi) aF[mi] = LDA256(4 + mi, 0);
    stage_half(4 * t + 7);
    __builtin_amdgcn_s_barrier();
    __builtin_amdgcn_s_setprio(1);
#pragma unroll
    for (int mi = 0; mi < 4; ++mi)
#pragma unroll
      for (int ni = 0; ni < 4; ++ni)
        acc[4 + mi][ni] = __builtin_amdgcn_mfma_f32_16x16x32_bf16(
            aF[mi], bF[ni], acc[4 + mi][ni], 0, 0, 0);
    __builtin_amdgcn_s_setprio(0);
    __builtin_amdgcn_s_barrier();
    // ---- phase 2: kk1, mi 0..3 ----
#pragma unroll
    for (int ni = 0; ni < 4; ++ni) bF[ni] = LDB256(ni, 1);
#pragma unroll
    for (int mi = 0; mi < 4; ++mi) aF[mi] = LDA256(mi, 1);
    stage_half(4 * t + 8);
    __builtin_amdgcn_s_barrier();
    __builtin_amdgcn_s_setprio(1);
#pragma unroll
    for (int mi = 0; mi < 4; ++mi)
#pragma unroll
      for (int ni = 0; ni < 4; ++ni)
        acc[mi][ni] = __builtin_amdgcn_mfma_f32_16x16x32_bf16(
            aF[mi], bF[ni], acc[mi][ni], 0, 0, 0);
    __builtin_amdgcn_s_setprio(0);
    __builtin_amdgcn_s_barrier();
    // ---- phase 3: kk1, mi 4..7 ----
#pragma unroll
    for (int mi = 0; mi < 4; ++mi) aF[mi] = LDA256(4 + mi, 1);
    stage_half(4 * t + 9);
    __builtin_amdgcn_s_barrier();
    __builtin_amdgcn_s_setprio(1);
#pragma unroll
    for (int mi = 0; mi < 4; ++mi)
#pragma unroll
      for (int ni = 0; ni < 4; ++ni)
        acc[4 + mi][ni] = __builtin_amdgcn_mfma_f32_16x16x32_bf16(
            aF[mi], bF[ni], acc[4 + mi][ni], 0, 0, 0);
    __builtin_amdgcn_s_setprio(0);
    if (t + 2 == NT)
      asm volatile("s_waitcnt vmcnt(0)\n\ts_barrier" ::: "memory");
    else if (t + 1 < NT)
      asm volatile("s_waitcnt vmcnt(4)\n\ts_barrier" ::: "memory");
#undef LDA256
#undef LDB256
  }

  int wm = (w >> 2) * 128, wn = (w & 3) * 64;
  if (FLAGS & 16) {
#pragma unroll
    for (int mi = 0; mi < 8; ++mi)
#pragma unroll
      for (int ni = 0; ni < 4; ++ni) {
        int colg = n0 + wn + ni * 16 + fr;
        if (colg < 1024) {
#pragma unroll
          for (int r = 0; r < 4; ++r) {
            int rowg = m0 + wm + mi * 16 + quad * 4 + r;
            ((u16*)out)[(size_t)rowg * 1024 + colg] = f2b(acc[mi][ni][r]);
          }
        } else {
          int hh = (colg - 1024) >> 6, ff = colg & 63;
          int rowg0 = m0 + wm + mi * 16 + quad * 4;
          int bb2 = rowg0 >> 12, tok = rowg0 & 4095;
          ushort4 pk;
          pk.x = f2b(acc[mi][ni][0]);
          pk.y = f2b(acc[mi][ni][1]);
          pk.z = f2b(acc[mi][ni][2]);
          pk.w = f2b(acc[mi][ni][3]);
          *(ushort4*)((u16*)out2 +
                      ((size_t)(bb2 * 8 + hh) * 64 + ff) * 4096 + tok) = pk;
        }
      }
    return;
  }

#pragma unroll
  for (int mi = 0; mi < 8; ++mi)
#pragma unroll
    for (int ni = 0; ni < 4; ++ni) {
      int colg = n0 + wn + ni * 16 + fr;
      float bv = (FLAGS & 1) ? bias[colg] : 0.0f;
#pragma unroll
      for (int r = 0; r < 4; ++r) {
        int rowg = m0 + wm + mi * 16 + quad * 4 + r;
        float val = acc[mi][ni][r] + bv;
        if (FLAGS & 2) val = fmaxf(val, 0.0f);
        if (FLAGS & 4) val += resid[(size_t)rowg * N + colg];
        if (FLAGS & 8)
          ((u16*)out)[(size_t)rowg * N + colg] = f2b(val);
        else
          ((float*)out)[(size_t)rowg * N + colg] = val;
      }
    }
}

// ---------------- MFMA local block attention ------------------------------
__global__ __launch_bounds__(128) void attn_mfma_kernel(
    const u16* __restrict__ qk, const u16* __restrict__ vt,
    const int* __restrict__ tokens, u16* __restrict__ o, int sh) {
  __shared__ __align__(16) u16 ps[2][64][72];
  __shared__ float kmask[64];
  int n = blockIdx.x, hg = blockIdx.y, b = blockIdx.z;
  int tid = threadIdx.x;
  int w = tid >> 6, lane = tid & 63;
  int head = hg * 2 + w;
  int fr = lane & 15, quad = lane >> 4;

  if (tid < 64) {
    int pp = n * 64 + tid - sh;
    kmask[tid] =
        (pp >= 0 && pp < TSEQ && tokens[(size_t)b * TSEQ + pp] > 0) ? 1.f : 0.f;
  }
  __syncthreads();

  const u16* qkb = qk + (size_t)b * TSEQ * 1024;

  f32x4 st[4][4];
  f32x4 zz = {0.f, 0.f, 0.f, 0.f};
#pragma unroll
  for (int i = 0; i < 4; ++i)
#pragma unroll
    for (int j = 0; j < 4; ++j) st[i][j] = zz;
#pragma unroll
  for (int kk = 0; kk < 2; ++kk) {
    short8 ka[4], qb[4];
#pragma unroll
    for (int mi = 0; mi < 4; ++mi) {
      int p = n * 64 + mi * 16 + fr - sh;
      ka[mi] = ld8g(qkb + (ptrdiff_t)p * 1024 + 512 + head * 64 + kk * 32 + quad * 8,
                    p >= 0 && p < TSEQ);
    }
#pragma unroll
    for (int ni = 0; ni < 4; ++ni) {
      int p = n * 64 + ni * 16 + fr - sh;
      qb[ni] = ld8g(qkb + (ptrdiff_t)p * 1024 + head * 64 + kk * 32 + quad * 8,
                    p >= 0 && p < TSEQ);
    }
#pragma unroll
    for (int mi = 0; mi < 4; ++mi)
#pragma unroll
      for (int ni = 0; ni < 4; ++ni)
        st[mi][ni] = __builtin_amdgcn_mfma_f32_16x16x32_bf16(
            ka[mi], qb[ni], st[mi][ni], 0, 0, 0);
  }

  float kmv[4][4];
#pragma unroll
  for (int mi = 0; mi < 4; ++mi)
#pragma unroll
    for (int r = 0; r < 4; ++r) kmv[mi][r] = kmask[mi * 16 + quad * 4 + r];
#pragma unroll
  for (int ni = 0; ni < 4; ++ni) {
    float mx = -3.0e38f;
#pragma unroll
    for (int mi = 0; mi < 4; ++mi)
#pragma unroll
      for (int r = 0; r < 4; ++r) {
        float s = (kmv[mi][r] > 0.f) ? st[mi][ni][r] * 0.125f : -1.0e9f;
        st[mi][ni][r] = s;
        mx = fmaxf(mx, s);
      }
    mx = fmaxf(mx, __shfl_xor(mx, 16, 64));
    mx = fmaxf(mx, __shfl_xor(mx, 32, 64));
    float sm = 0.f;
#pragma unroll
    for (int mi = 0; mi < 4; ++mi)
#pragma unroll
      for (int r = 0; r < 4; ++r) {
        float e = __expf(st[mi][ni][r] - mx);
        st[mi][ni][r] = e;
        sm += e;
      }
    sm += __shfl_xor(sm, 16, 64);
    sm += __shfl_xor(sm, 32, 64);
    float inv = 1.0f / sm;
#pragma unroll
    for (int mi = 0; mi < 4; ++mi)
#pragma unroll
      for (int r = 0; r < 4; ++r) st[mi][ni][r] *= inv;
  }

#pragma unroll
  for (int mi = 0; mi < 4; ++mi)
#pragma unroll
    for (int ni = 0; ni < 4; ++ni) {
      uint2 pk;
      pk.x = (u32)f2b(st[mi][ni][0]) | ((u32)f2b(st[mi][ni][1]) << 16);
      pk.y = (u32)f2b(st[mi][ni][2]) | ((u32)f2b(st[mi][ni][3]) << 16);
      *(uint2*)&ps[w][ni * 16 + fr][mi * 16 + quad * 4] = pk;
    }
  __syncthreads();

  f32x4 oc[4][4];
#pragma unroll
  for (int i = 0; i < 4; ++i)
#pragma unroll
    for (int j = 0; j < 4; ++j) oc[i][j] = zz;
  const u16* vtb = vt + (size_t)(b * 8 + head) * 64 * 4096;
#pragma unroll
  for (int kk = 0; kk < 2; ++kk) {
    short8 pa[4], vb[4];
#pragma unroll
    for (int mi = 0; mi < 4; ++mi)
      pa[mi] = *(const short8*)&ps[w][mi * 16 + fr][kk * 32 + quad * 8];
    int key0 = n * 64 - sh + kk * 32 + quad * 8;
    bool kok = (key0 >= 0) && (key0 < TSEQ);
#pragma unroll
    for (int ni = 0; ni < 4; ++ni)
      vb[ni] = ld8g(vtb + (size_t)(ni * 16 + fr) * 4096 + key0, kok);
#pragma unroll
    for (int mi = 0; mi < 4; ++mi)
#pragma unroll
      for (int ni = 0; ni < 4; ++ni)
        oc[mi][ni] = __builtin_amdgcn_mfma_f32_16x16x32_bf16(
            pa[mi], vb[ni], oc[mi][ni], 0, 0, 0);
  }

#pragma unroll
  for (int mi = 0; mi < 4; ++mi)
#pragma unroll
    for (int ni = 0; ni < 4; ++ni)
#pragma unroll
      for (int r = 0; r < 4; ++r) {
        int q = mi * 16 + quad * 4 + r;
        int p = n * 64 + q - sh;
        if (p >= 0 && p < TSEQ)
          o[((size_t)(b * TSEQ + p)) * DMODEL + head * 64 + ni * 16 + fr] =
              f2b(oc[mi][ni][r]);
      }
}

// ---------------------------------------------------------------------------
extern "C" void kernel_launch(void* const* d_in, const int* in_sizes, int n_in,
                              void* d_out, int out_size, void* d_ws, size_t ws_size,
                              hipStream_t stream) {
  (void)in_sizes; (void)n_in; (void)out_size; (void)ws_size;
  const int*   tokens = (const int*)d_in[0];
  const float* embed  = (const float*)d_in[1];
  const float* wq = (const float*)d_in[2];
  const float* wk = (const float*)d_in[3];
  const float* wv = (const float*)d_in[4];
  const float* wo = (const float*)d_in[5];
  const float* ln1_s = (const float*)d_in[6];
  const float* ln1_b = (const float*)d_in[7];
  const float* ln2_s = (const float*)d_in[8];
  const float* ln2_b = (const float*)d_in[9];
  const float* w1 = (const float*)d_in[10];
  const float* b1 = (const float*)d_in[11];
  const float* w2 = (const float*)d_in[12];
  const float* b2 = (const float*)d_in[13];
  const float* lnf_s = (const float*)d_in[14];
  const float* lnf_b = (const float*)d_in[15];

  char* ws = (char*)d_ws;
  const size_t MB = 1024ull * 1024ull;
  float* x     = (float*)(ws + 0);        // 32 MB fp32 residual
  u16* h       = (u16*)(ws + 32 * MB);    // 16 MB bf16 LN out
  u16* qk      = (u16*)(ws + 48 * MB);    // 33.5 MB bf16 [B*T][1024]
  u16* vt      = (u16*)(ws + 82 * MB);    // 16.8 MB bf16 V^T
  u16* obuf    = (u16*)(ws + 99 * MB);    // 16.8 MB bf16
  u16* hidden  = (u16*)(ws + 48 * MB);    // 64 MB (aliases qk/vt/obuf, disjoint in time)
  u16* wqkv_bt = (u16*)(ws + 116 * MB);   // 9 MB
  u16* wo_bt   = (u16*)(ws + 126 * MB);   // 3.1 MB
  u16* w1_bt   = (u16*)(ws + 130 * MB);   // 12.6 MB
  u16* w2_bt   = (u16*)(ws + 143 * MB);   // 12.6 MB (total ~156 MB)

  transpose_convert_all<<<dim3(768, 6), 256, 0, stream>>>(
      wq, wk, wv, wo, w1, w2, wqkv_bt, wo_bt, w1_bt, w2_bt);

  embed_pe_kernel<<<16384, 128, 0, stream>>>(tokens, embed, x);

  for (int l = 0; l < NLAYER; ++l) {
    int sh = (l & 1) ? 32 : 0;
    int nb = (l & 1) ? 65 : 64;
    ln_kernel<true><<<4096, 256, 0, stream>>>(x, ln1_s + l * 512, ln1_b + l * 512, h);
    gemm256_kernel<16><<<dim3(6, 64), 512, 0, stream>>>(
        h, wqkv_bt + (size_t)l * 1536 * 512, nullptr, nullptr, qk, vt,
        16384, 1536, 512);
    attn_mfma_kernel<<<dim3(nb, 4, 4), 128, 0, stream>>>(qk, vt, tokens, obuf, sh);
    gemm_kernel<4><<<dim3(4, 128), 256, 0, stream>>>(
        obuf, wo_bt + (size_t)l * 512 * 512, nullptr, x, x, nullptr,
        16384, 512, 512);
    ln_kernel<true><<<4096, 256, 0, stream>>>(x, ln2_s + l * 512, ln2_b + l * 512, h);
    gemm256_kernel<1 | 2 | 8><<<dim3(8, 64), 512, 0, stream>>>(
        h, w1_bt + (size_t)l * 2048 * 512, b1 + l * 2048, nullptr, hidden, nullptr,
        16384, 2048, 512);
    gemm_kernel<1 | 4><<<dim3(4, 128), 256, 0, stream>>>(
        hidden, w2_bt + (size_t)l * 512 * 2048, b2 + l * 512, x, x, nullptr,
        16384, 512, 2048);
  }
  ln_kernel<false><<<4096, 256, 0, stream>>>(x, lnf_s, lnf_b, d_out);
}